// Round 2
// baseline (118.141 us; speedup 1.0000x reference)
//
#include <hip/hip_runtime.h>
#include <hip/hip_bf16.h>
#include <stdint.h>

// Problem constants (fixed by setup_inputs)
#define N_IMG 4
#define A_DIM 256
#define HW    65536            // 256*256 pixels per image
#define C_CLS 19
#define NPIX  (N_IMG*HW)       // 262144
#define CHUNK 512              // pixels per chunk in stats kernel
#define NCHUNK (NPIX/CHUNK)    // 512
#define TSPLIT 16              // first-stage reduction split

// workspace layout (bytes)
#define OFF_LAB 0                       // uint8 labels, 262144 B
#define OFF_CNT 262144                  // int counts[20]
#define OFF_COV 262272                  // float CoV[19][256]
#define OFF_S   281728                  // float S05[20][19]
#define OFF_P2  283392                  // float2 p2[16][19][256]
#define OFF_P1  905984                  // float2 partial[nblk][19][256]
#define P1_ROW_BYTES (C_CLS*2*A_DIM*4)  // 38912 bytes per block row

// ---------------- Kernel A: label downsample + histogram ----------------
__global__ __launch_bounds__(256) void kA_labels(const int* __restrict__ tgt,
                                                 uint8_t* __restrict__ lab,
                                                 int* __restrict__ counts) {
    __shared__ int hist[20];
    int t = threadIdx.x;
    if (t < 20) hist[t] = 0;
    __syncthreads();
    int idx = blockIdx.x * 256 + t;           // [0, NPIX)
    int n = idx >> 16;
    int p = idx & 65535;
    int h = p >> 8, w = p & 255;
    // nearest: tgt[n, 2h, 2w]; image is 512x512
    int v = tgt[(n << 18) + (h << 10) + (w << 1)];
    int lu = (v == 255) ? 19 : v;             // lab_u in [0,19]
    lab[idx] = (uint8_t)lu;
    atomicAdd(&hist[lu], 1);
    __syncthreads();
    if (t < 20) atomicAdd(&counts[t], hist[t]);
}

// ---------------- Kernel B: per-class sum & sumsq ----------------
__device__ __forceinline__ void load_group(float4 (&buf)[8], const float4* f4, int g) {
#pragma unroll
    for (int q = 0; q < 8; ++q) buf[q] = f4[g * 8 + q];
}

__device__ __forceinline__ void proc_group(const float4 (&buf)[8], int g,
                                           const unsigned* labw, float2* bins, int t) {
#pragma unroll
    for (int q = 0; q < 8; ++q) {
        unsigned lw = labw[g * 8 + q];        // 4 labels, wave-uniform value
        const float4 vv = buf[q];
#pragma unroll
        for (int i = 0; i < 4; ++i) {
            int lb = (lw >> (8 * i)) & 255;   // 0..19
            float v = (i == 0) ? vv.x : (i == 1) ? vv.y : (i == 2) ? vv.z : vv.w;
            float2* bp = &bins[lb * A_DIM + t];   // bank = t%32 -> conflict-free
            float2 b = *bp;
            b.x += v;
            b.y = fmaf(v, v, b.y);
            *bp = b;
        }
    }
}

__global__ __launch_bounds__(256) void kB_stats(const float* __restrict__ features,
                                                const uint8_t* __restrict__ lab,
                                                float2* __restrict__ partial, int nblk) {
    __shared__ float2 bins[20 * A_DIM];       // 40960 B (class 19 accumulated, discarded)
    __shared__ unsigned labw[CHUNK / 4];      // 128 packed label words
    int t = threadIdx.x;
    for (int i = t; i < 20 * A_DIM; i += 256) bins[i] = make_float2(0.f, 0.f);

    for (int ch = blockIdx.x; ch < NCHUNK; ch += nblk) {
        int n = ch >> 7;                      // 128 chunks per image
        int p0 = (ch & 127) * CHUNK;
        __syncthreads();
        if (t < CHUNK / 4)
            labw[t] = ((const unsigned*)(lab + n * HW + p0))[t];
        __syncthreads();

        const float4* f4 = (const float4*)(features + (((size_t)(n * A_DIM + t)) << 16) + p0);
        float4 bufA[8], bufB[8];
        load_group(bufA, f4, 0);
#pragma unroll 1
        for (int g = 0; g < 16; g += 2) {
            load_group(bufB, f4, g + 1);      // prefetch while processing A
            proc_group(bufA, g, labw, bins, t);
            if (g + 2 < 16) load_group(bufA, f4, g + 2);
            proc_group(bufB, g + 1, labw, bins, t);
        }
    }
    __syncthreads();
    // write classes 0..18 (contiguous prefix of bins)
    float2* dst = partial + (size_t)blockIdx.x * (C_CLS * A_DIM);
    for (int i = t; i < C_CLS * A_DIM; i += 256) dst[i] = bins[i];
}

// ---------------- Kernel C1a: first-stage partial reduction ----------------
__global__ __launch_bounds__(256) void kC1a(const float2* __restrict__ partial,
                                            float2* __restrict__ p2, int nblk) {
    int c = blockIdx.x;            // 0..18
    int s = blockIdx.y;            // 0..15
    int a = threadIdx.x;
    int per = nblk / TSPLIT;
    float sum = 0.f, sq = 0.f;
    for (int b = s * per; b < (s + 1) * per; ++b) {
        float2 v = partial[(size_t)b * (C_CLS * A_DIM) + c * A_DIM + a];
        sum += v.x; sq += v.y;
    }
    p2[(s * C_CLS + c) * A_DIM + a] = make_float2(sum, sq);
}

// ---------------- Kernel C1b: finalize CoV ----------------
__global__ __launch_bounds__(256) void kC1b(const float2* __restrict__ p2,
                                            const int* __restrict__ counts,
                                            const float* __restrict__ Amount,
                                            const float* __restrict__ Ave,
                                            const float* __restrict__ CoVin,
                                            float* __restrict__ CoV) {
    int c = blockIdx.x, a = threadIdx.x;
    float sum = 0.f, sq = 0.f;
#pragma unroll
    for (int s = 0; s < TSPLIT; ++s) {
        float2 v = p2[(s * C_CLS + c) * A_DIM + a];
        sum += v.x; sq += v.y;
    }
    float cnt = (float)counts[c];
    float denom = fmaxf(cnt, 1.0f);
    float ave = sum / denom;
    float var = (sq - 2.0f * ave * sum + ave * ave * cnt) / denom;
    float dw = cnt + Amount[c];
    float w = (dw != 0.0f) ? (cnt / dw) : 0.0f;   // nan(0/0) -> 0 rule
    float d = Ave[c * A_DIM + a] - ave;
    CoV[c * A_DIM + a] = CoVin[c * A_DIM + a] * (1.0f - w) + var * w
                       + w * (1.0f - w) * d * d;
}

// ---------------- Kernel C2: S05[k][c] = 0.5*ratio*sum_a (W[c]-W[k])^2*CoV[k] ----------------
__global__ __launch_bounds__(256) void kC2(const float* __restrict__ CoV,
                                           const float* __restrict__ W,
                                           const float* __restrict__ ratio,
                                           float* __restrict__ S) {
    __shared__ float red[C_CLS][4];
    int k = blockIdx.x;            // 0..19
    int t = threadIdx.x;
    if (k == 19) {                 // ignore-row: sigma2 contribution is zero
        if (t < C_CLS) S[19 * C_CLS + t] = 0.0f;
        return;
    }
    float cv = CoV[k * A_DIM + t];
    float wk = W[k * A_DIM + t];
    int lane = t & 63, wv = t >> 6;
    for (int c = 0; c < C_CLS; ++c) {
        float d = W[c * A_DIM + t] - wk;
        float term = d * d * cv;
#pragma unroll
        for (int o = 32; o > 0; o >>= 1) term += __shfl_xor(term, o, 64);
        if (lane == 0) red[c][wv] = term;
    }
    __syncthreads();
    if (t < C_CLS)
        S[k * C_CLS + t] = 0.5f * ratio[0] * (red[t][0] + red[t][1] + red[t][2] + red[t][3]);
}

// ---------------- Kernel D: out = y + S05[lab][c] ----------------
__global__ __launch_bounds__(256) void kD_apply(const float* __restrict__ y,
                                                const uint8_t* __restrict__ lab,
                                                const float* __restrict__ S,
                                                float* __restrict__ out) {
    __shared__ float sS[20 * C_CLS];
    int t = threadIdx.x;
    for (int i = t; i < 20 * C_CLS; i += 256) sS[i] = S[i];
    __syncthreads();
    int idx4 = blockIdx.x * 256 + t;          // float4 index
    if (idx4 >= NPIX * C_CLS / 4) return;     // exact grid; never taken
    int plane = idx4 >> 14;                   // (n*19 + c); 16384 float4 per plane
    int p4 = idx4 & 16383;
    int n = plane / C_CLS;
    int c = plane - n * C_CLS;
    float4 yv = ((const float4*)y)[idx4];
    unsigned lw = *(((const unsigned*)(lab + n * HW)) + p4);
    float4 o;
    o.x = yv.x + sS[((lw      ) & 255) * C_CLS + c];
    o.y = yv.y + sS[((lw >> 8 ) & 255) * C_CLS + c];
    o.z = yv.z + sS[((lw >> 16) & 255) * C_CLS + c];
    o.w = yv.w + sS[((lw >> 24)      ) * C_CLS + c];
    ((float4*)out)[idx4] = o;
}

// ---------------- launcher ----------------
extern "C" void kernel_launch(void* const* d_in, const int* in_sizes, int n_in,
                              void* d_out, int out_size, void* d_ws, size_t ws_size,
                              hipStream_t stream) {
    const float* features = (const float*)d_in[0];
    const float* fc_weight = (const float*)d_in[1];
    const float* y         = (const float*)d_in[2];
    const float* Ave       = (const float*)d_in[3];
    const float* CoVin     = (const float*)d_in[4];
    const float* Amount    = (const float*)d_in[5];
    const float* ratio     = (const float*)d_in[6];
    const int*   target_x  = (const int*)d_in[7];
    float* out             = (float*)d_out;

    char* ws = (char*)d_ws;
    uint8_t* lab    = (uint8_t*)(ws + OFF_LAB);
    int*     counts = (int*)(ws + OFF_CNT);
    float*   CoV    = (float*)(ws + OFF_COV);
    float*   S      = (float*)(ws + OFF_S);
    float2*  p2     = (float2*)(ws + OFF_P2);
    float2*  partial= (float2*)(ws + OFF_P1);

    size_t avail = (ws_size > (size_t)OFF_P1) ? (ws_size - OFF_P1) : 0;
    int nblk = (int)(avail / P1_ROW_BYTES);
    if (nblk > 512) nblk = 512;
    nblk &= ~15;                 // multiple of TSPLIT
    if (nblk < 16) nblk = 16;    // minimal fallback

    (void)hipMemsetAsync(counts, 0, 20 * sizeof(int), stream);
    kA_labels<<<NPIX / 256, 256, 0, stream>>>(target_x, lab, counts);
    kB_stats<<<nblk, 256, 0, stream>>>(features, lab, partial, nblk);
    kC1a<<<dim3(C_CLS, TSPLIT), 256, 0, stream>>>(partial, p2, nblk);
    kC1b<<<C_CLS, 256, 0, stream>>>(p2, counts, Amount, Ave, CoVin, CoV);
    kC2<<<20, 256, 0, stream>>>(CoV, fc_weight, ratio, S);
    kD_apply<<<(NPIX * C_CLS / 4 + 255) / 256, 256, 0, stream>>>(y, lab, S, d_out ? out : out);
}